// Round 16
// baseline (244.464 us; speedup 1.0000x reference)
//
#include <hip/hip_runtime.h>
#include <hip/hip_bf16.h>

// B=16, H=W=128, N=16384, DIM=64, HEADS=2, HD=32, MLP_H=256
#define NB 16
#define NT 16384
#define NTOK (NB * NT)

typedef __hip_bfloat16 bf16;
typedef __attribute__((ext_vector_type(8))) short short8;
typedef __attribute__((ext_vector_type(4))) float f32x4;

static __device__ __forceinline__ f32x4 MFMA(short8 a, short8 b, f32x4 c) {
    return __builtin_amdgcn_mfma_f32_16x16x32_bf16(a, b, c, 0, 0, 0);
}
static __device__ __forceinline__ short bfs(float f) {
    union { bf16 h; short s; } u; u.h = __float2bfloat16(f); return u.s;
}
static __device__ __forceinline__ float sbf(short s) {
    union { bf16 h; short s; } u; u.s = s; return __bfloat162float(u.h);
}
static __device__ __forceinline__ bf16 f2bf(float v) { return __float2bfloat16(v); }
static __device__ __forceinline__ float us2f(unsigned short u) {
    union { unsigned int i; float f; } x; x.i = ((unsigned int)u) << 16; return x.f;
}
// e5m2 fp8 codec via native _Float16: encode = f32->f16, round mantissa,
// keep top byte (round carry propagates into exponent correctly).
static __device__ __forceinline__ unsigned char e8(float v) {
    union { _Float16 h; unsigned short u; } x; x.h = (_Float16)v;
    return (unsigned char)((x.u + 0x80) >> 8);
}
static __device__ __forceinline__ float d8(unsigned char e) {
    union { _Float16 h; unsigned short u; } x; x.u = (unsigned short)(e << 8);
    return (float)x.h;
}

// max(x,0)^p with 0 at 0
static __device__ __forceinline__ float safe_pow(float x, float p) {
    return (x > 0.f) ? __builtin_amdgcn_exp2f(p * __builtin_amdgcn_logf(x)) : 0.f;
}
static __device__ __forceinline__ float sigm(float y) {  // 1/(1+e^-y)
    return __builtin_amdgcn_rcpf(1.f + __builtin_amdgcn_exp2f(-1.44269504f * y));
}

// swizzled byte offset inside a [rows][32-tok] bf16 region (64B rows)
static __device__ __forceinline__ int swb(int row, int tok) {
    return row * 64 + ((tok * 2) ^ (((row >> 1) & 3) << 4));
}

// ---------------------------------------------------------------------------
// k0: pack weights into MFMA B-fragment order (bf16)
// ---------------------------------------------------------------------------
__global__ __launch_bounds__(256)
void k0_prep(const float* __restrict__ w_qg, const float* __restrict__ w_kv,
             const float* __restrict__ w_fc1, const float* __restrict__ w_fc2,
             short* __restrict__ wqk_f, short* __restrict__ wf1_f, short* __restrict__ wf2_f)
{
    int idx = blockIdx.x * 256 + threadIdx.x;
    if (idx < 16384) {
        int k = idx >> 8, col = idx & 255;
        float wv = (col < 128) ? w_qg[k * 128 + col] : w_kv[k * 128 + col - 128];
        int ct = col >> 4, ks = k >> 5, lane = (col & 15) + 16 * ((k & 31) >> 3), j = k & 7;
        wqk_f[((ct * 2 + ks) * 64 + lane) * 8 + j] = bfs(wv);
    } else if (idx < 32768) {
        int i2 = idx - 16384, k = i2 >> 8, col = i2 & 255;
        int ct = col >> 4, ks = k >> 5, lane = (col & 15) + 16 * ((k & 31) >> 3), j = k & 7;
        wf1_f[((ct * 2 + ks) * 64 + lane) * 8 + j] = bfs(w_fc1[k * 256 + col]);
    } else if (idx < 49152) {
        int i2 = idx - 32768, k = i2 >> 6, col = i2 & 63;
        int ct2 = col >> 4, ks = k >> 5, lane = (col & 15) + 16 * ((k & 31) >> 3), j = k & 7;
        wf2_f[((ct2 * 8 + ks) * 64 + lane) * 8 + j] = bfs(w_fc2[k * 64 + col]);
    }
}

// ---------------------------------------------------------------------------
// k1: LN1 + qg/kv projections (MFMA) + k features + per-(b,h) reductions (MFMA)
// 32 tokens (two A-tiles) per wave-iteration: each B-fragment LDS read feeds
// two MFMAs (halves LDS-pipe traffic per token). grid (16, B), 8 iters.
// q/gate/v stored as fp8-e5m2; reductions flushed via atomicAdd.
// ---------------------------------------------------------------------------
__global__ __launch_bounds__(256)
void k1_proj(const float* __restrict__ x,
             const float* __restrict__ ln1_g, const float* __restrict__ ln1_b,
             const short* __restrict__ wqk_f,
             const float* __restrict__ pos_enc,
             const float* __restrict__ scale_p, const float* __restrict__ power_p,
             unsigned char* __restrict__ qb8, unsigned char* __restrict__ gbuf8,
             unsigned char* __restrict__ vbuf8,
             float* __restrict__ km_g, float* __restrict__ kv_g)
{
    __shared__ __align__(16) unsigned char lds[49152];
    __shared__ __align__(16) short wqk_s[16384];   // 32 KB
    const int tid = threadIdx.x;
    const int b = blockIdx.y, chunk = blockIdx.x;
    const int w = tid >> 6, l = tid & 63, l15 = l & 15, g = l >> 4;
    unsigned char* kft = lds + w * 12288;   // [2h][64 fd][32 tok] bf16 swizzled
    unsigned char* vt  = kft + 8192;        // [2h][32 vc][32 tok] bf16 swizzled

    // stage wqk fragment table
    #pragma unroll
    for (int i = 0; i < 8; ++i)
        ((uint4*)wqk_s)[tid * 8 + i] = ((const uint4*)wqk_f)[tid * 8 + i];

    float g1v[16], b1v[16];
    #pragma unroll
    for (int j = 0; j < 8; j++) {
        g1v[j]     = ln1_g[g * 8 + j];      b1v[j]     = ln1_b[g * 8 + j];
        g1v[8 + j] = ln1_g[32 + g * 8 + j]; b1v[8 + j] = ln1_b[32 + g * 8 + j];
    }
    float isc[4], pwk[4];
    #pragma unroll
    for (int ct = 0; ct < 4; ct++) {
        int ch = l15 + 16 * ct;
        float s = scale_p[ch];
        float sp = 0.69314718f * __builtin_amdgcn_logf(1.f + __builtin_amdgcn_exp2f(1.44269504f * s));
        isc[ct] = __builtin_amdgcn_rcpf(sp);
        pwk[ct] = 1.f + 4.f * sigm(power_p[ch]);
    }

    f32x4 acc[2][2][4];
    #pragma unroll
    for (int s = 0; s < 2; s++)
        #pragma unroll
        for (int h = 0; h < 2; h++)
            #pragma unroll
            for (int mt = 0; mt < 4; mt++) { f32x4 z = {0.f,0.f,0.f,0.f}; acc[s][h][mt] = z; }
    float kmp[4] = {0.f,0.f,0.f,0.f}, kmn[4] = {0.f,0.f,0.f,0.f};

    __syncthreads();

    for (int it = 0; it < 8; ++it) {
        const int tokbase = chunk * 1024 + (it * 4 + w) * 32;
        // ---- LN1 for two 16-token tiles -> A-fragments
        short8 A0[2], A1[2];
        #pragma unroll
        for (int t = 0; t < 2; ++t) {
            const size_t rowb = (size_t)b * NT + tokbase + t * 16;
            const float* xrow = x + (rowb + l15) * 64;
            float4 t0 = *(const float4*)(xrow + g * 8);
            float4 t1 = *(const float4*)(xrow + g * 8 + 4);
            float4 t2 = *(const float4*)(xrow + 32 + g * 8);
            float4 t3 = *(const float4*)(xrow + 32 + g * 8 + 4);
            float xa8[8] = {t0.x,t0.y,t0.z,t0.w,t1.x,t1.y,t1.z,t1.w};
            float xb8[8] = {t2.x,t2.y,t2.z,t2.w,t3.x,t3.y,t3.z,t3.w};
            float s1 = 0.f, s2 = 0.f;
            #pragma unroll
            for (int j = 0; j < 8; j++) {
                s1 += xa8[j] + xb8[j];
                s2 += xa8[j] * xa8[j] + xb8[j] * xb8[j];
            }
            s1 += __shfl_xor(s1, 16, 64); s1 += __shfl_xor(s1, 32, 64);
            s2 += __shfl_xor(s2, 16, 64); s2 += __shfl_xor(s2, 32, 64);
            float mu = s1 * 0.015625f;
            float var = s2 * 0.015625f - mu * mu;
            float rs = rsqrtf(var + 1e-5f);
            #pragma unroll
            for (int j = 0; j < 8; j++) {
                A0[t][j] = bfs((xa8[j] - mu) * rs * g1v[j] + b1v[j]);
                A1[t][j] = bfs((xb8[j] - mu) * rs * g1v[8 + j] + b1v[8 + j]);
            }
        }
        // ---- projections: each B-fragment pair feeds both tiles
        #pragma unroll
        for (int ct = 0; ct < 16; ct++) {
            short8 f0 = *(const short8*)(wqk_s + (ct * 2 + 0) * 512 + l * 8);
            short8 f1 = *(const short8*)(wqk_s + (ct * 2 + 1) * 512 + l * 8);
            f32x4 c[2];
            #pragma unroll
            for (int t = 0; t < 2; t++) {
                f32x4 z = {0.f,0.f,0.f,0.f};
                z = MFMA(A0[t], f0, z);
                c[t] = MFMA(A1[t], f1, z);
            }
            if (ct < 4) {            // q -> fp8
                #pragma unroll
                for (int t = 0; t < 2; t++)
                    #pragma unroll
                    for (int r = 0; r < 4; r++)
                        qb8[((size_t)b * NT + tokbase + t * 16 + g * 4 + r) * 64 + l15 + 16 * ct]
                            = e8(c[t][r] * isc[ct]);
            } else if (ct < 8) {     // gate -> fp8
                #pragma unroll
                for (int t = 0; t < 2; t++)
                    #pragma unroll
                    for (int r = 0; r < 4; r++)
                        gbuf8[((size_t)b * NT + tokbase + t * 16 + g * 4 + r) * 64 + l15 + 16 * (ct - 4)]
                            = e8(c[t][r]);
            } else if (ct < 12) {    // k -> features
                const int ctk = ct - 8, kchan = l15 + 16 * ctk;
                const int hh = kchan >> 5, d = kchan & 31;
                #pragma unroll
                for (int t = 0; t < 2; t++)
                    #pragma unroll
                    for (int r = 0; r < 4; r++) {
                        int n = tokbase + t * 16 + g * 4 + r;
                        float kvl = (c[t][r] + pos_enc[(size_t)n * 64 + kchan]) * isc[ctk];
                        float kp = safe_pow(kvl, pwk[ctk]);
                        float kn = safe_pow(-kvl, pwk[ctk]);
                        kmp[ctk] += kp; kmn[ctk] += kn;
                        int tk = t * 16 + g * 4 + r;
                        *(short*)(kft + swb(hh * 64 + d, tk))      = bfs(kp);
                        *(short*)(kft + swb(hh * 64 + 32 + d, tk)) = bfs(kn);
                    }
            } else {                 // v -> fp8 global, bf16 LDS
                const int ctv = ct - 12, vchan = l15 + 16 * ctv;
                const int hh = vchan >> 5, vc = vchan & 31;
                #pragma unroll
                for (int t = 0; t < 2; t++)
                    #pragma unroll
                    for (int r = 0; r < 4; r++) {
                        int tk = t * 16 + g * 4 + r;
                        vbuf8[((size_t)b * NT + tokbase + t * 16 + g * 4 + r) * 64 + vchan] = e8(c[t][r]);
                        *(short*)(vt + swb(hh * 32 + vc, tk)) = bfs(c[t][r]);
                    }
            }
        }
        // ---- reduction over the 32 staged tokens (every iteration)
        #pragma unroll
        for (int h = 0; h < 2; h++) {
            int rv0 = h * 32 + l15, rv1 = h * 32 + 16 + l15;
            short8 Bv0 = *(const short8*)(vt + rv0 * 64 + ((g * 16) ^ (((rv0 >> 1) & 3) << 4)));
            short8 Bv1 = *(const short8*)(vt + rv1 * 64 + ((g * 16) ^ (((rv1 >> 1) & 3) << 4)));
            #pragma unroll
            for (int mt = 0; mt < 4; mt++) {
                int rk = h * 64 + mt * 16 + l15;
                short8 Ak = *(const short8*)(kft + rk * 64 + ((g * 16) ^ (((rk >> 1) & 3) << 4)));
                acc[0][h][mt] = MFMA(Ak, Bv0, acc[0][h][mt]);
                acc[1][h][mt] = MFMA(Ak, Bv1, acc[1][h][mt]);
            }
        }
    }
    // flush reductions via atomics (64 distinct addresses per instruction)
    const float invN = 1.f / 16384.f;
    float* kvb = kv_g + (size_t)b * 4096;
    #pragma unroll
    for (int s = 0; s < 2; s++)
        #pragma unroll
        for (int h = 0; h < 2; h++)
            #pragma unroll
            for (int mt = 0; mt < 4; mt++)
                #pragma unroll
                for (int r = 0; r < 4; r++)
                    atomicAdd(&kvb[((s * 2 + h) * 64 + mt * 16 + g * 4 + r) * 16 + l15],
                              acc[s][h][mt][r] * invN);
    #pragma unroll
    for (int ct = 0; ct < 4; ct++) {
        kmp[ct] += __shfl_xor(kmp[ct], 16, 64); kmp[ct] += __shfl_xor(kmp[ct], 32, 64);
        kmn[ct] += __shfl_xor(kmn[ct], 16, 64); kmn[ct] += __shfl_xor(kmn[ct], 32, 64);
    }
    if (g == 0) {
        #pragma unroll
        for (int ct = 0; ct < 4; ct++) {
            int kchan = l15 + 16 * ct, hh = kchan >> 5, d = kchan & 31;
            atomicAdd(&km_g[b * 128 + hh * 64 + d],      kmp[ct] * invN);
            atomicAdd(&km_g[b * 128 + hh * 64 + 32 + d], kmn[ct] * invN);
        }
    }
}

// ---------------------------------------------------------------------------
// k2: 5x5 depthwise conv. Block = 32x8 spatial tile of one image.
// Input fp8 (decoded to bf16 tile in LDS); output fp8.
// ---------------------------------------------------------------------------
__global__ __launch_bounds__(256)
void k2_dwc(const unsigned char* __restrict__ vbuf8,
            const float* __restrict__ dwc_w, const float* __restrict__ dwc_b,
            unsigned char* __restrict__ vdb8)
{
    __shared__ __align__(16) unsigned short tile[12][36][64];   // 55296 B
    const int tid = threadIdx.x;
    const int b = blockIdx.y;
    const int ty = blockIdx.x >> 2, tx = blockIdx.x & 3;
    const int y0 = ty * 8, x0 = tx * 32;

    #pragma unroll
    for (int i = 0; i < 14; ++i) {
        int cid = i * 256 + tid;          // 3456 chunks of 8 channels
        if (cid < 3456) {
            int yy = cid / 288;           // 288 = 36*8 chunks per row
            int rem = cid - yy * 288;
            int xx = rem >> 3;
            int c8 = rem & 7;
            int Y = y0 - 2 + yy, X = x0 - 2 + xx;
            uint2 val = make_uint2(0u, 0u);
            if ((unsigned)Y < 128u && (unsigned)X < 128u)
                val = *(const uint2*)(vbuf8 + (((size_t)b * NT + Y * 128 + X) * 64 + c8 * 8));
            unsigned short ob[8];
            #pragma unroll
            for (int k = 0; k < 4; k++) {
                ob[k]     = (unsigned short)bfs(d8((unsigned char)(val.x >> (8 * k))));
                ob[4 + k] = (unsigned short)bfs(d8((unsigned char)(val.y >> (8 * k))));
            }
            uint4 o;
            o.x = (unsigned)ob[0] | ((unsigned)ob[1] << 16);
            o.y = (unsigned)ob[2] | ((unsigned)ob[3] << 16);
            o.z = (unsigned)ob[4] | ((unsigned)ob[5] << 16);
            o.w = (unsigned)ob[6] | ((unsigned)ob[7] << 16);
            *(uint4*)(&tile[yy][xx][c8 * 8]) = o;
        }
    }
    __syncthreads();

    const int w = tid >> 6, c = tid & 63, d = c & 31;
    float wt[25];
    #pragma unroll
    for (int k = 0; k < 25; k++) wt[k] = dwc_w[d * 25 + k];
    const float bias = dwc_b[d];

    #pragma unroll
    for (int yl2 = 0; yl2 < 2; ++yl2) {
        const int yl = w * 2 + yl2;
        float cw[5][5];
        #pragma unroll
        for (int xx = 0; xx < 4; ++xx)
            #pragma unroll
            for (int ky = 0; ky < 5; ++ky)
                cw[ky][xx] = us2f(tile[yl + ky][xx][c]);
        #pragma unroll
        for (int xl = 0; xl < 32; ++xl) {
            const int jn = (xl + 4) % 5;
            #pragma unroll
            for (int ky = 0; ky < 5; ++ky)
                cw[ky][jn] = us2f(tile[yl + ky][xl + 4][c]);
            float acc = bias;
            #pragma unroll
            for (int ky = 0; ky < 5; ++ky)
                #pragma unroll
                for (int kx = 0; kx < 5; ++kx)
                    acc += wt[ky * 5 + kx] * cw[ky][(xl + kx) % 5];
            const int Y = y0 + yl, X = x0 + xl;
            vdb8[((size_t)b * NT + Y * 128 + X) * 64 + c] = e8(acc);
        }
    }
}

// ---------------------------------------------------------------------------
// k3: attn apply + gate + proj + residual + LN2 + MLP + residual (MFMA)
// 1024 threads (16 waves), grid (16, B); 4 iterations/wave with explicit
// double-buffered prefetch of next-iteration global loads (SSA, full unroll).
// All weight frags LDS-resident; fp8 activations; out via tbuf bounce.
// ---------------------------------------------------------------------------
__global__ __launch_bounds__(1024, 4)
void k3_main(const float* __restrict__ x,
             const unsigned char* __restrict__ qb8, const unsigned char* __restrict__ gbuf8,
             const unsigned char* __restrict__ vdb8,
             const float* __restrict__ km_g, const float* __restrict__ kv_g,
             const float* __restrict__ power_p,
             const float* __restrict__ w_proj, const float* __restrict__ b_proj,
             const float* __restrict__ ln2_g, const float* __restrict__ ln2_b,
             const short* __restrict__ wf1_f, const short* __restrict__ wf2_f,
             const float* __restrict__ b_fc1, const float* __restrict__ b_fc2,
             float* __restrict__ out)
{
    __shared__ __align__(16) short wkv_s[8][512];            // 8 KB
    __shared__ __align__(16) short wp_s[8][512];             // 8 KB
    __shared__ __align__(16) short wf1_s[16384];             // 32 KB
    __shared__ __align__(16) short wf2_s[16384];             // 32 KB
    __shared__ __align__(16) unsigned char tbuf[16][2048];   // 32 KB

    const int tid = threadIdx.x, b = blockIdx.y, chunk = blockIdx.x;
    const int w = tid >> 6, l = tid & 63, l15 = l & 15, g = l >> 4;
    unsigned char* tb = tbuf[w];

    // ---- stage kv / proj fragments (512 slots each; split across 1024 thr)
    if (tid < 512) {
        int frag = tid >> 6, lane = tid & 63;
        int s2h = frag >> 1, ks = frag & 1;
        short8 v;
        #pragma unroll
        for (int j = 0; j < 8; ++j) {
            int idx = s2h * 1024 + (ks * 32 + (lane >> 4) * 8 + j) * 16 + (lane & 15);
            v[j] = bfs(kv_g[(size_t)b * 4096 + idx]);
        }
        *(short8*)&wkv_s[frag][lane * 8] = v;
    } else {
        int t2 = tid - 512;
        int frag = t2 >> 6, lane = t2 & 63;
        int ct = frag >> 1, ks = frag & 1;
        short8 v;
        #pragma unroll
        for (int j = 0; j < 8; ++j) {
            int idx = (ks * 32 + (lane >> 4) * 8 + j) * 64 + ct * 16 + (lane & 15);
            v[j] = bfs(w_proj[idx]);
        }
        *(short8*)&wp_s[frag][lane * 8] = v;
    }
    // ---- stage fc1/fc2 fragment tables (already packed), coalesced
    #pragma unroll
    for (int i = 0; i < 2; ++i) {
        ((uint4*)wf1_s)[tid * 2 + i] = ((const uint4*)wf1_f)[tid * 2 + i];
        ((uint4*)wf2_s)[tid * 2 + i] = ((const uint4*)wf2_f)[tid * 2 + i];
    }

    // ---- km denominator fragments in registers (cols 0/1 used)
    short8 Kden[2][2];
    #pragma unroll
    for (int h = 0; h < 2; ++h)
        #pragma unroll
        for (int f = 0; f < 2; ++f)
            #pragma unroll
            for (int j = 0; j < 8; ++j) {
                int d = g * 8 + j;
                float v = 0.f;
                if (l15 == 0)      v = km_g[b * 128 + h * 64 + (f ? 32 + d : d)];
                else if (l15 == 1) v = km_g[b * 128 + h * 64 + (f ? d : 32 + d)];
                Kden[h][f][j] = bfs(v);
            }

    float pw3[2][8];
    #pragma unroll
    for (int h = 0; h < 2; h++)
        #pragma unroll
        for (int j = 0; j < 8; j++)
            pw3[h][j] = 1.f + 4.f * sigm(power_p[h * 32 + g * 8 + j]);
    float bpj[4], g2[4], b2[4], bfc2v[4];
    #pragma unroll
    for (int ct = 0; ct < 4; ct++) {
        int ch = l15 + 16 * ct;
        bpj[ct] = b_proj[ch]; g2[ct] = ln2_g[ch]; b2[ct] = ln2_b[ch]; bfc2v[ct] = b_fc2[ch];
    }
    float bf1v[16];
    #pragma unroll
    for (int ct = 0; ct < 16; ct++) bf1v[ct] = b_fc1[ct * 16 + l15];

    __syncthreads();

    // ---- per-iteration global load (issues 3 fp8 uint2 loads + 16 x floats)
    auto LOADIT = [&](int itx, uint2* qv, uint2* gv, uint2* vv, float (*xvv)[4]) {
        const int tok0 = chunk * 1024 + (itx * 16 + w) * 16;
        const size_t rowb = (size_t)b * NT + tok0;
        const size_t goff = (rowb + l15) * 64;
        #pragma unroll
        for (int ks = 0; ks < 2; ks++) {
            qv[ks] = *(const uint2*)(qb8   + goff + ks * 32 + g * 8);
            gv[ks] = *(const uint2*)(gbuf8 + goff + ks * 32 + g * 8);
            vv[ks] = *(const uint2*)(vdb8  + goff + ks * 32 + g * 8);
        }
        #pragma unroll
        for (int ct = 0; ct < 4; ct++)
            #pragma unroll
            for (int r = 0; r < 4; r++)
                xvv[ct][r] = x[(rowb + g * 4 + r) * 64 + l15 + 16 * ct];
    };

    uint2 qv[2], gv[2], vv[2];
    float xv[4][4];
    LOADIT(0, qv, gv, vv, xv);

    #pragma unroll
    for (int it = 0; it < 4; ++it) {
        // ---- prefetch next iteration's loads before current compute
        uint2 qv2[2], gv2[2], vv2[2];
        float xv2[4][4];
        if (it < 3) LOADIT(it + 1, qv2, gv2, vv2, xv2);

        const int tok0 = chunk * 1024 + (it * 16 + w) * 16;
        const size_t rowb = (size_t)b * NT + tok0;

        // ---- decode fp8 activations
        float qf[2][8], vdf[2][8], ggf[2][8];
        #pragma unroll
        for (int ks = 0; ks < 2; ks++) {
            #pragma unroll
            for (int k = 0; k < 4; k++) {
                qf[ks][k]      = d8((unsigned char)(qv[ks].x >> (8 * k)));
                qf[ks][4 + k]  = d8((unsigned char)(qv[ks].y >> (8 * k)));
                ggf[ks][k]     = d8((unsigned char)(gv[ks].x >> (8 * k)));
                ggf[ks][4 + k] = d8((unsigned char)(gv[ks].y >> (8 * k)));
                vdf[ks][k]     = d8((unsigned char)(vv[ks].x >> (8 * k)));
                vdf[ks][4 + k] = d8((unsigned char)(vv[ks].y >> (8 * k)));
            }
        }

        // ---- phase A: q features + denominator via 2 MFMAs
        short8 Fqp[2], Fqn[2];
        f32x4 dn[2];
        #pragma unroll
        for (int h = 0; h < 2; h++) {
            #pragma unroll
            for (int j = 0; j < 8; j++) {
                float q = qf[h][j];
                Fqp[h][j] = bfs(safe_pow(q, pw3[h][j]));
                Fqn[h][j] = bfs(safe_pow(-q, pw3[h][j]));
            }
            f32x4 z4 = {0.f, 0.f, 0.f, 0.f};
            z4 = MFMA(Fqp[h], Kden[h][0], z4);
            dn[h] = MFMA(Fqn[h], Kden[h][1], z4);
        }

        // ---- phase B: attention MFMA (kv frags from LDS)
        f32x4 at[4];
        #pragma unroll
        for (int hs = 0; hs < 4; hs++) { f32x4 z4 = {0.f,0.f,0.f,0.f}; at[hs] = z4; }
        #pragma unroll
        for (int h = 0; h < 2; h++) {
            short8 b00 = *(const short8*)&wkv_s[(0 * 2 + h) * 2 + 0][l * 8];
            short8 b01 = *(const short8*)&wkv_s[(0 * 2 + h) * 2 + 1][l * 8];
            short8 b10 = *(const short8*)&wkv_s[(1 * 2 + h) * 2 + 0][l * 8];
            short8 b11 = *(const short8*)&wkv_s[(1 * 2 + h) * 2 + 1][l * 8];
            at[h*2+0] = MFMA(Fqp[h], b00, at[h*2+0]);
            at[h*2+0] = MFMA(Fqn[h], b01, at[h*2+0]);
            at[h*2+1] = MFMA(Fqn[h], b10, at[h*2+1]);
            at[h*2+1] = MFMA(Fqp[h], b11, at[h*2+1]);
        }

        // ---- phase C: z-scale via shfl of dn, transpose, + dwc, * gate
        #pragma unroll
        for (int hs = 0; hs < 4; hs++) {
            int h = hs >> 1, s = hs & 1;
            int cb = h * 32 + s * 16;
            #pragma unroll
            for (int r = 0; r < 4; r++) {
                float dv = __shfl(dn[h][r], g * 16 + s, 64);
                float zz = __builtin_amdgcn_rcpf(dv + 1e-6f);
                int tok = g * 4 + r;
                *(short*)(tb + tok * 128 + (((cb + l15) * 2) ^ ((tok & 7) << 4))) = bfs(at[hs][r] * zz);
            }
        }
        short8 Ap[2];
        #pragma unroll
        for (int ks = 0; ks < 2; ks++) {
            short8 t8 = *(short8*)(tb + l15 * 128 + ((ks * 64 + g * 16) ^ ((l15 & 7) << 4)));
            #pragma unroll
            for (int j = 0; j < 8; j++)
                Ap[ks][j] = bfs((sbf(t8[j]) + vdf[ks][j]) * ggf[ks][j]);
        }

        // ---- phase D: proj (frags from LDS)
        f32x4 pc[4];
        #pragma unroll
        for (int ct = 0; ct < 4; ct++) {
            short8 w0 = *(const short8*)&wp_s[ct * 2 + 0][l * 8];
            short8 w1 = *(const short8*)&wp_s[ct * 2 + 1][l * 8];
            f32x4 z4 = {0.f,0.f,0.f,0.f};
            z4 = MFMA(Ap[0], w0, z4);
            pc[ct] = MFMA(Ap[1], w1, z4);
        }

        // ---- phase E: residual + LN2 + write h2 transpose directly
        float xm[4][4];
        #pragma unroll
        for (int ct = 0; ct < 4; ct++)
            #pragma unroll
            for (int r = 0; r < 4; r++)
                xm[ct][r] = xv[ct][r] + pc[ct][r] + bpj[ct];
        #pragma unroll
        for (int r = 0; r < 4; r++) {
            float s1 = xm[0][r] + xm[1][r] + xm[2][r] + xm[3][r];
            float s2 = xm[0][r]*xm[0][r] + xm[1][r]*xm[1][r] + xm[2][r]*xm[2][r] + xm[3][r]*xm[3][r];
            #pragma unroll
            for (int m = 1; m < 16; m <<= 1) { s1 += __shfl_xor(s1, m, 64); s2 += __shfl_xor(s2, m, 64); }
            float mu = s1 * 0.015625f;
            float var = s2 * 0.015625f - mu * mu;
            float rs = rsqrtf(var + 1e-5f);
            int tok = g * 4 + r;
            #pragma unroll
            for (int ct = 0; ct < 4; ct++) {
                float h2 = (xm[ct][r] - mu) * rs * g2[ct] + b2[ct];
                *(short*)(tb + tok * 128 + (((ct * 16 + l15) * 2) ^ ((tok & 7) << 4))) = bfs(h2);
            }
        }
        short8 Ah[2];
        #pragma unroll
        for (int ks = 0; ks < 2; ks++)
            Ah[ks] = *(short8*)(tb + l15 * 128 + ((ks * 64 + g * 16) ^ ((l15 & 7) << 4)));

        // ---- phase G: fc1 + gelu + fc2 (all frags from LDS)
        f32x4 a2[4];
        #pragma unroll
        for (int ct = 0; ct < 4; ct++) { f32x4 z4 = {0.f,0.f,0.f,0.f}; a2[ct] = z4; }
        #pragma unroll
        for (int g4 = 0; g4 < 4; g4++) {
            f32x4 fc[4];
            #pragma unroll
            for (int ctl = 0; ctl < 4; ctl++) {
                int ct = g4 * 4 + ctl;
                short8 f0 = *(const short8*)(wf1_s + (ct * 2 + 0) * 512 + l * 8);
                short8 f1 = *(const short8*)(wf1_s + (ct * 2 + 1) * 512 + l * 8);
                f32x4 z4 = {0.f,0.f,0.f,0.f};
                z4 = MFMA(Ah[0], f0, z4);
                fc[ctl] = MFMA(Ah[1], f1, z4);
            }
            #pragma unroll
            for (int ctl = 0; ctl < 4; ctl++)
                #pragma unroll
                for (int r = 0; r < 4; r++) {
                    float mv = fc[ctl][r] + bf1v[g4 * 4 + ctl];
                    float gl = mv * __builtin_amdgcn_rcpf(1.f +
                        __builtin_amdgcn_exp2f(mv * (-2.30220825f - 0.10294385f * mv * mv)));
                    int tok = g * 4 + r;
                    *(short*)(tb + tok * 128 + (((ctl * 16 + l15) * 2) ^ ((tok & 7) << 4))) = bfs(gl);
                }
            #pragma unroll
            for (int ksl = 0; ksl < 2; ksl++) {
                short8 Ag = *(short8*)(tb + l15 * 128 + ((ksl * 64 + g * 16) ^ ((l15 & 7) << 4)));
                int ks = g4 * 2 + ksl;
                #pragma unroll
                for (int ct2 = 0; ct2 < 4; ct2++) {
                    short8 wv = *(const short8*)(wf2_s + (ct2 * 8 + ks) * 512 + l * 8);
                    a2[ct2] = MFMA(Ag, wv, a2[ct2]);
                }
            }
        }

        // ---- phase H: bounce through tbuf, plain f32x4 stores
        float* tb32 = (float*)tb;   // 2048 B = 16 tok x 32 ch f32
        #pragma unroll
        for (int half = 0; half < 2; ++half) {
            #pragma unroll
            for (int ctl = 0; ctl < 2; ++ctl) {
                int ct = half * 2 + ctl;
                #pragma unroll
                for (int r = 0; r < 4; r++)
                    tb32[(g * 4 + r) * 32 + ctl * 16 + l15] = xm[ct][r] + a2[ct][r] + bfc2v[ct];
            }
            #pragma unroll
            for (int i = 0; i < 2; ++i) {
                f32x4 v = *(f32x4*)&tb32[i * 256 + l * 4];
                *(f32x4*)(out + (rowb + i * 8 + (l >> 3)) * 64 + half * 32 + (l & 7) * 4) = v;
            }
        }

        // ---- rotate prefetched buffers
        #pragma unroll
        for (int ks = 0; ks < 2; ks++) { qv[ks] = qv2[ks]; gv[ks] = gv2[ks]; vv[ks] = vv2[ks]; }
        #pragma unroll
        for (int ct = 0; ct < 4; ct++)
            #pragma unroll
            for (int r = 0; r < 4; r++)
                xv[ct][r] = xv2[ct][r];
    }
}

// ---------------------------------------------------------------------------
extern "C" void kernel_launch(void* const* d_in, const int* in_sizes, int n_in,
                              void* d_out, int out_size, void* d_ws, size_t ws_size,
                              hipStream_t stream)
{
    const float* x       = (const float*)d_in[0];
    const float* ln1_g   = (const float*)d_in[3];
    const float* ln1_b   = (const float*)d_in[4];
    const float* w_qg    = (const float*)d_in[5];
    const float* w_kv    = (const float*)d_in[6];
    const float* pos     = (const float*)d_in[7];
    const float* scale_p = (const float*)d_in[8];
    const float* power_p = (const float*)d_in[9];
    const float* dwc_w   = (const float*)d_in[10];
    const float* dwc_b   = (const float*)d_in[11];
    const float* w_proj  = (const float*)d_in[12];
    const float* b_proj  = (const float*)d_in[13];
    const float* ln2_g   = (const float*)d_in[14];
    const float* ln2_b   = (const float*)d_in[15];
    const float* w_fc1   = (const float*)d_in[16];
    const float* b_fc1   = (const float*)d_in[17];
    const float* w_fc2   = (const float*)d_in[18];
    const float* b_fc2   = (const float*)d_in[19];
    float* out = (float*)d_out;

    // workspace layout: all activation intermediates fp8 -> footprint ~134MB
    size_t ntc = (size_t)NTOK * 64;
    unsigned char* qb8   = (unsigned char*)d_ws;
    unsigned char* vbuf8 = qb8 + ntc;
    unsigned char* gbuf8 = vbuf8 + ntc;
    unsigned char* vdb8  = gbuf8 + ntc;
    float* km_g = (float*)(vdb8 + ntc);              // [B][128]
    float* kv_g = km_g + (size_t)NB * 128;           // [B][4096]
    short* wqk_f = (short*)(kv_g + (size_t)NB * 4096);
    short* wf1_f = wqk_f + 16384;
    short* wf2_f = wf1_f + 16384;

    hipMemsetAsync(km_g, 0, ((size_t)NB * 128 + (size_t)NB * 4096) * sizeof(float), stream);

    k0_prep<<<dim3(192), 256, 0, stream>>>(w_qg, w_kv, w_fc1, w_fc2, wqk_f, wf1_f, wf2_f);
    k1_proj<<<dim3(16, NB), 256, 0, stream>>>(x, ln1_g, ln1_b, wqk_f, pos, scale_p, power_p,
                                              qb8, gbuf8, vbuf8, km_g, kv_g);
    k2_dwc<<<dim3(64, NB), 256, 0, stream>>>(vbuf8, dwc_w, dwc_b, vdb8);
    k3_main<<<dim3(16, NB), 1024, 0, stream>>>(x, qb8, gbuf8, vdb8, km_g, kv_g, power_p,
                                               w_proj, b_proj, ln2_g, ln2_b,
                                               wf1_f, wf2_f, b_fc1, b_fc2, out);
}

// Round 17
// 232.633 us; speedup vs baseline: 1.0509x; 1.0509x over previous
//
#include <hip/hip_runtime.h>
#include <hip/hip_bf16.h>

// B=16, H=W=128, N=16384, DIM=64, HEADS=2, HD=32, MLP_H=256
#define NB 16
#define NT 16384
#define NTOK (NB * NT)

typedef __hip_bfloat16 bf16;
typedef __attribute__((ext_vector_type(8))) short short8;
typedef __attribute__((ext_vector_type(4))) float f32x4;

static __device__ __forceinline__ f32x4 MFMA(short8 a, short8 b, f32x4 c) {
    return __builtin_amdgcn_mfma_f32_16x16x32_bf16(a, b, c, 0, 0, 0);
}
static __device__ __forceinline__ short bfs(float f) {
    union { bf16 h; short s; } u; u.h = __float2bfloat16(f); return u.s;
}
static __device__ __forceinline__ float sbf(short s) {
    union { bf16 h; short s; } u; u.s = s; return __bfloat162float(u.h);
}
static __device__ __forceinline__ bf16 f2bf(float v) { return __float2bfloat16(v); }
static __device__ __forceinline__ float us2f(unsigned short u) {
    union { unsigned int i; float f; } x; x.i = ((unsigned int)u) << 16; return x.f;
}
// e5m2 fp8 codec via native _Float16: encode = f32->f16, round mantissa,
// keep top byte (round carry propagates into exponent correctly).
static __device__ __forceinline__ unsigned char e8(float v) {
    union { _Float16 h; unsigned short u; } x; x.h = (_Float16)v;
    return (unsigned char)((x.u + 0x80) >> 8);
}
static __device__ __forceinline__ float d8(unsigned char e) {
    union { _Float16 h; unsigned short u; } x; x.u = (unsigned short)(e << 8);
    return (float)x.h;
}

// max(x,0)^p with 0 at 0
static __device__ __forceinline__ float safe_pow(float x, float p) {
    return (x > 0.f) ? __builtin_amdgcn_exp2f(p * __builtin_amdgcn_logf(x)) : 0.f;
}
static __device__ __forceinline__ float sigm(float y) {  // 1/(1+e^-y)
    return __builtin_amdgcn_rcpf(1.f + __builtin_amdgcn_exp2f(-1.44269504f * y));
}

// swizzled byte offset inside a [rows][32-tok] bf16 region (64B rows)
static __device__ __forceinline__ int swb(int row, int tok) {
    return row * 64 + ((tok * 2) ^ (((row >> 1) & 3) << 4));
}

// ---------------------------------------------------------------------------
// k0: pack weights into MFMA B-fragment order (bf16)
// ---------------------------------------------------------------------------
__global__ __launch_bounds__(256)
void k0_prep(const float* __restrict__ w_qg, const float* __restrict__ w_kv,
             const float* __restrict__ w_fc1, const float* __restrict__ w_fc2,
             short* __restrict__ wqk_f, short* __restrict__ wf1_f, short* __restrict__ wf2_f)
{
    int idx = blockIdx.x * 256 + threadIdx.x;
    if (idx < 16384) {
        int k = idx >> 8, col = idx & 255;
        float wv = (col < 128) ? w_qg[k * 128 + col] : w_kv[k * 128 + col - 128];
        int ct = col >> 4, ks = k >> 5, lane = (col & 15) + 16 * ((k & 31) >> 3), j = k & 7;
        wqk_f[((ct * 2 + ks) * 64 + lane) * 8 + j] = bfs(wv);
    } else if (idx < 32768) {
        int i2 = idx - 16384, k = i2 >> 8, col = i2 & 255;
        int ct = col >> 4, ks = k >> 5, lane = (col & 15) + 16 * ((k & 31) >> 3), j = k & 7;
        wf1_f[((ct * 2 + ks) * 64 + lane) * 8 + j] = bfs(w_fc1[k * 256 + col]);
    } else if (idx < 49152) {
        int i2 = idx - 32768, k = i2 >> 6, col = i2 & 63;
        int ct2 = col >> 4, ks = k >> 5, lane = (col & 15) + 16 * ((k & 31) >> 3), j = k & 7;
        wf2_f[((ct2 * 8 + ks) * 64 + lane) * 8 + j] = bfs(w_fc2[k * 64 + col]);
    }
}

// ---------------------------------------------------------------------------
// k1: LN1 + qg/kv projections (MFMA) + k features + per-(b,h) reductions (MFMA)
// wqk fragment table staged in LDS. Reductions flushed via atomicAdd.
// q/gate/v stored as fp8-e5m2.
// ---------------------------------------------------------------------------
__global__ __launch_bounds__(256)
void k1_proj(const float* __restrict__ x,
             const float* __restrict__ ln1_g, const float* __restrict__ ln1_b,
             const short* __restrict__ wqk_f,
             const float* __restrict__ pos_enc,
             const float* __restrict__ scale_p, const float* __restrict__ power_p,
             unsigned char* __restrict__ qb8, unsigned char* __restrict__ gbuf8,
             unsigned char* __restrict__ vbuf8,
             float* __restrict__ km_g, float* __restrict__ kv_g)
{
    __shared__ __align__(16) unsigned char lds[49152];
    __shared__ __align__(16) short wqk_s[16384];   // 32 KB
    const int tid = threadIdx.x;
    const int b = blockIdx.y, chunk = blockIdx.x;
    const int w = tid >> 6, l = tid & 63, l15 = l & 15, g = l >> 4;
    unsigned char* kft = lds + w * 12288;   // [2h][64 fd][32 tok] bf16 swizzled
    unsigned char* vt  = kft + 8192;        // [2h][32 vc][32 tok] bf16 swizzled

    // stage wqk fragment table
    #pragma unroll
    for (int i = 0; i < 8; ++i)
        ((uint4*)wqk_s)[tid * 8 + i] = ((const uint4*)wqk_f)[tid * 8 + i];

    float g1v[16], b1v[16];
    #pragma unroll
    for (int j = 0; j < 8; j++) {
        g1v[j]     = ln1_g[g * 8 + j];      b1v[j]     = ln1_b[g * 8 + j];
        g1v[8 + j] = ln1_g[32 + g * 8 + j]; b1v[8 + j] = ln1_b[32 + g * 8 + j];
    }
    float isc[4], pwk[4];
    #pragma unroll
    for (int ct = 0; ct < 4; ct++) {
        int ch = l15 + 16 * ct;
        float s = scale_p[ch];
        float sp = 0.69314718f * __builtin_amdgcn_logf(1.f + __builtin_amdgcn_exp2f(1.44269504f * s));
        isc[ct] = __builtin_amdgcn_rcpf(sp);
        pwk[ct] = 1.f + 4.f * sigm(power_p[ch]);
    }

    f32x4 acc[2][2][4];
    #pragma unroll
    for (int s = 0; s < 2; s++)
        #pragma unroll
        for (int h = 0; h < 2; h++)
            #pragma unroll
            for (int mt = 0; mt < 4; mt++) { f32x4 z = {0.f,0.f,0.f,0.f}; acc[s][h][mt] = z; }
    float kmp[4] = {0.f,0.f,0.f,0.f}, kmn[4] = {0.f,0.f,0.f,0.f};

    __syncthreads();

    for (int it = 0; it < 8; ++it) {
        const int tok0 = chunk * 512 + (it * 4 + w) * 16;
        const size_t rowb = (size_t)b * NT + tok0;
        const float* xrow = x + (rowb + l15) * 64;
        float4 t0 = *(const float4*)(xrow + g * 8);
        float4 t1 = *(const float4*)(xrow + g * 8 + 4);
        float4 t2 = *(const float4*)(xrow + 32 + g * 8);
        float4 t3 = *(const float4*)(xrow + 32 + g * 8 + 4);
        float xa8[8] = {t0.x,t0.y,t0.z,t0.w,t1.x,t1.y,t1.z,t1.w};
        float xb8[8] = {t2.x,t2.y,t2.z,t2.w,t3.x,t3.y,t3.z,t3.w};
        float s1 = 0.f, s2 = 0.f;
        #pragma unroll
        for (int j = 0; j < 8; j++) {
            s1 += xa8[j] + xb8[j];
            s2 += xa8[j] * xa8[j] + xb8[j] * xb8[j];
        }
        s1 += __shfl_xor(s1, 16, 64); s1 += __shfl_xor(s1, 32, 64);
        s2 += __shfl_xor(s2, 16, 64); s2 += __shfl_xor(s2, 32, 64);
        float mu = s1 * 0.015625f;
        float var = s2 * 0.015625f - mu * mu;
        float rs = rsqrtf(var + 1e-5f);
        short8 A0, A1;
        #pragma unroll
        for (int j = 0; j < 8; j++) {
            A0[j] = bfs((xa8[j] - mu) * rs * g1v[j] + b1v[j]);
            A1[j] = bfs((xb8[j] - mu) * rs * g1v[8 + j] + b1v[8 + j]);
        }
        const int tokp = (it & 1) * 16;
        #pragma unroll
        for (int ct = 0; ct < 16; ct++) {
            short8 f0 = *(const short8*)(wqk_s + (ct * 2 + 0) * 512 + l * 8);
            short8 f1 = *(const short8*)(wqk_s + (ct * 2 + 1) * 512 + l * 8);
            f32x4 c = {0.f,0.f,0.f,0.f};
            c = MFMA(A0, f0, c);
            c = MFMA(A1, f1, c);
            if (ct < 4) {            // q -> fp8
                #pragma unroll
                for (int r = 0; r < 4; r++)
                    qb8[(rowb + g * 4 + r) * 64 + l15 + 16 * ct] = e8(c[r] * isc[ct]);
            } else if (ct < 8) {     // gate -> fp8
                #pragma unroll
                for (int r = 0; r < 4; r++)
                    gbuf8[(rowb + g * 4 + r) * 64 + l15 + 16 * (ct - 4)] = e8(c[r]);
            } else if (ct < 12) {    // k -> features
                const int ctk = ct - 8, kchan = l15 + 16 * ctk;
                const int hh = kchan >> 5, d = kchan & 31;
                #pragma unroll
                for (int r = 0; r < 4; r++) {
                    int n = tok0 + g * 4 + r;
                    float kvl = (c[r] + pos_enc[(size_t)n * 64 + kchan]) * isc[ctk];
                    float kp = safe_pow(kvl, pwk[ctk]);
                    float kn = safe_pow(-kvl, pwk[ctk]);
                    kmp[ctk] += kp; kmn[ctk] += kn;
                    int tk = tokp + g * 4 + r;
                    *(short*)(kft + swb(hh * 64 + d, tk))      = bfs(kp);
                    *(short*)(kft + swb(hh * 64 + 32 + d, tk)) = bfs(kn);
                }
            } else {                 // v -> fp8 global, bf16 LDS
                const int ctv = ct - 12, vchan = l15 + 16 * ctv;
                const int hh = vchan >> 5, vc = vchan & 31;
                #pragma unroll
                for (int r = 0; r < 4; r++) {
                    int tk = tokp + g * 4 + r;
                    vbuf8[(rowb + g * 4 + r) * 64 + vchan] = e8(c[r]);
                    *(short*)(vt + swb(hh * 32 + vc, tk)) = bfs(c[r]);
                }
            }
        }
        if (it & 1) {  // reduction over 32 staged tokens
            #pragma unroll
            for (int h = 0; h < 2; h++) {
                int rv0 = h * 32 + l15, rv1 = h * 32 + 16 + l15;
                short8 Bv0 = *(const short8*)(vt + rv0 * 64 + ((g * 16) ^ (((rv0 >> 1) & 3) << 4)));
                short8 Bv1 = *(const short8*)(vt + rv1 * 64 + ((g * 16) ^ (((rv1 >> 1) & 3) << 4)));
                #pragma unroll
                for (int mt = 0; mt < 4; mt++) {
                    int rk = h * 64 + mt * 16 + l15;
                    short8 Ak = *(const short8*)(kft + rk * 64 + ((g * 16) ^ (((rk >> 1) & 3) << 4)));
                    acc[0][h][mt] = MFMA(Ak, Bv0, acc[0][h][mt]);
                    acc[1][h][mt] = MFMA(Ak, Bv1, acc[1][h][mt]);
                }
            }
        }
    }
    // flush reductions via atomics (64 distinct addresses per instruction)
    const float invN = 1.f / 16384.f;
    float* kvb = kv_g + (size_t)b * 4096;
    #pragma unroll
    for (int s = 0; s < 2; s++)
        #pragma unroll
        for (int h = 0; h < 2; h++)
            #pragma unroll
            for (int mt = 0; mt < 4; mt++)
                #pragma unroll
                for (int r = 0; r < 4; r++)
                    atomicAdd(&kvb[((s * 2 + h) * 64 + mt * 16 + g * 4 + r) * 16 + l15],
                              acc[s][h][mt][r] * invN);
    #pragma unroll
    for (int ct = 0; ct < 4; ct++) {
        kmp[ct] += __shfl_xor(kmp[ct], 16, 64); kmp[ct] += __shfl_xor(kmp[ct], 32, 64);
        kmn[ct] += __shfl_xor(kmn[ct], 16, 64); kmn[ct] += __shfl_xor(kmn[ct], 32, 64);
    }
    if (g == 0) {
        #pragma unroll
        for (int ct = 0; ct < 4; ct++) {
            int kchan = l15 + 16 * ct, hh = kchan >> 5, d = kchan & 31;
            atomicAdd(&km_g[b * 128 + hh * 64 + d],      kmp[ct] * invN);
            atomicAdd(&km_g[b * 128 + hh * 64 + 32 + d], kmn[ct] * invN);
        }
    }
}

// ---------------------------------------------------------------------------
// k2: 5x5 depthwise conv. Block = 32x8 spatial tile of one image.
// Input fp8 (decoded to bf16 tile in LDS); output fp8.
// ---------------------------------------------------------------------------
__global__ __launch_bounds__(256)
void k2_dwc(const unsigned char* __restrict__ vbuf8,
            const float* __restrict__ dwc_w, const float* __restrict__ dwc_b,
            unsigned char* __restrict__ vdb8)
{
    __shared__ __align__(16) unsigned short tile[12][36][64];   // 55296 B
    const int tid = threadIdx.x;
    const int b = blockIdx.y;
    const int ty = blockIdx.x >> 2, tx = blockIdx.x & 3;
    const int y0 = ty * 8, x0 = tx * 32;

    #pragma unroll
    for (int i = 0; i < 14; ++i) {
        int cid = i * 256 + tid;          // 3456 chunks of 8 channels
        if (cid < 3456) {
            int yy = cid / 288;           // 288 = 36*8 chunks per row
            int rem = cid - yy * 288;
            int xx = rem >> 3;
            int c8 = rem & 7;
            int Y = y0 - 2 + yy, X = x0 - 2 + xx;
            uint2 val = make_uint2(0u, 0u);
            if ((unsigned)Y < 128u && (unsigned)X < 128u)
                val = *(const uint2*)(vbuf8 + (((size_t)b * NT + Y * 128 + X) * 64 + c8 * 8));
            unsigned short ob[8];
            #pragma unroll
            for (int k = 0; k < 4; k++) {
                ob[k]     = (unsigned short)bfs(d8((unsigned char)(val.x >> (8 * k))));
                ob[4 + k] = (unsigned short)bfs(d8((unsigned char)(val.y >> (8 * k))));
            }
            uint4 o;
            o.x = (unsigned)ob[0] | ((unsigned)ob[1] << 16);
            o.y = (unsigned)ob[2] | ((unsigned)ob[3] << 16);
            o.z = (unsigned)ob[4] | ((unsigned)ob[5] << 16);
            o.w = (unsigned)ob[6] | ((unsigned)ob[7] << 16);
            *(uint4*)(&tile[yy][xx][c8 * 8]) = o;
        }
    }
    __syncthreads();

    const int w = tid >> 6, c = tid & 63, d = c & 31;
    float wt[25];
    #pragma unroll
    for (int k = 0; k < 25; k++) wt[k] = dwc_w[d * 25 + k];
    const float bias = dwc_b[d];

    #pragma unroll
    for (int yl2 = 0; yl2 < 2; ++yl2) {
        const int yl = w * 2 + yl2;
        float cw[5][5];
        #pragma unroll
        for (int xx = 0; xx < 4; ++xx)
            #pragma unroll
            for (int ky = 0; ky < 5; ++ky)
                cw[ky][xx] = us2f(tile[yl + ky][xx][c]);
        #pragma unroll
        for (int xl = 0; xl < 32; ++xl) {
            const int jn = (xl + 4) % 5;
            #pragma unroll
            for (int ky = 0; ky < 5; ++ky)
                cw[ky][jn] = us2f(tile[yl + ky][xl + 4][c]);
            float acc = bias;
            #pragma unroll
            for (int ky = 0; ky < 5; ++ky)
                #pragma unroll
                for (int kx = 0; kx < 5; ++kx)
                    acc += wt[ky * 5 + kx] * cw[ky][(xl + kx) % 5];
            const int Y = y0 + yl, X = x0 + xl;
            vdb8[((size_t)b * NT + Y * 128 + X) * 64 + c] = e8(acc);
        }
    }
}

// ---------------------------------------------------------------------------
// k3: attn apply + gate + proj + residual + LN2 + MLP + residual (MFMA)
// 1024 threads (16 waves), grid (16, B); 4 iterations/wave with explicit
// double-buffered prefetch of next-iteration global loads (SSA, full unroll).
// All weight frags LDS-resident; fp8 activations; out via tbuf bounce.
// ---------------------------------------------------------------------------
__global__ __launch_bounds__(1024, 4)
void k3_main(const float* __restrict__ x,
             const unsigned char* __restrict__ qb8, const unsigned char* __restrict__ gbuf8,
             const unsigned char* __restrict__ vdb8,
             const float* __restrict__ km_g, const float* __restrict__ kv_g,
             const float* __restrict__ power_p,
             const float* __restrict__ w_proj, const float* __restrict__ b_proj,
             const float* __restrict__ ln2_g, const float* __restrict__ ln2_b,
             const short* __restrict__ wf1_f, const short* __restrict__ wf2_f,
             const float* __restrict__ b_fc1, const float* __restrict__ b_fc2,
             float* __restrict__ out)
{
    __shared__ __align__(16) short wkv_s[8][512];            // 8 KB
    __shared__ __align__(16) short wp_s[8][512];             // 8 KB
    __shared__ __align__(16) short wf1_s[16384];             // 32 KB
    __shared__ __align__(16) short wf2_s[16384];             // 32 KB
    __shared__ __align__(16) unsigned char tbuf[16][2048];   // 32 KB

    const int tid = threadIdx.x, b = blockIdx.y, chunk = blockIdx.x;
    const int w = tid >> 6, l = tid & 63, l15 = l & 15, g = l >> 4;
    unsigned char* tb = tbuf[w];

    // ---- stage kv / proj fragments (512 slots each; split across 1024 thr)
    if (tid < 512) {
        int frag = tid >> 6, lane = tid & 63;
        int s2h = frag >> 1, ks = frag & 1;
        short8 v;
        #pragma unroll
        for (int j = 0; j < 8; ++j) {
            int idx = s2h * 1024 + (ks * 32 + (lane >> 4) * 8 + j) * 16 + (lane & 15);
            v[j] = bfs(kv_g[(size_t)b * 4096 + idx]);
        }
        *(short8*)&wkv_s[frag][lane * 8] = v;
    } else {
        int t2 = tid - 512;
        int frag = t2 >> 6, lane = t2 & 63;
        int ct = frag >> 1, ks = frag & 1;
        short8 v;
        #pragma unroll
        for (int j = 0; j < 8; ++j) {
            int idx = (ks * 32 + (lane >> 4) * 8 + j) * 64 + ct * 16 + (lane & 15);
            v[j] = bfs(w_proj[idx]);
        }
        *(short8*)&wp_s[frag][lane * 8] = v;
    }
    // ---- stage fc1/fc2 fragment tables (already packed), coalesced
    #pragma unroll
    for (int i = 0; i < 2; ++i) {
        ((uint4*)wf1_s)[tid * 2 + i] = ((const uint4*)wf1_f)[tid * 2 + i];
        ((uint4*)wf2_s)[tid * 2 + i] = ((const uint4*)wf2_f)[tid * 2 + i];
    }

    // ---- km denominator fragments in registers (cols 0/1 used)
    short8 Kden[2][2];
    #pragma unroll
    for (int h = 0; h < 2; ++h)
        #pragma unroll
        for (int f = 0; f < 2; ++f)
            #pragma unroll
            for (int j = 0; j < 8; ++j) {
                int d = g * 8 + j;
                float v = 0.f;
                if (l15 == 0)      v = km_g[b * 128 + h * 64 + (f ? 32 + d : d)];
                else if (l15 == 1) v = km_g[b * 128 + h * 64 + (f ? d : 32 + d)];
                Kden[h][f][j] = bfs(v);
            }

    float pw3[2][8];
    #pragma unroll
    for (int h = 0; h < 2; h++)
        #pragma unroll
        for (int j = 0; j < 8; j++)
            pw3[h][j] = 1.f + 4.f * sigm(power_p[h * 32 + g * 8 + j]);
    float bpj[4], g2[4], b2[4], bfc2v[4];
    #pragma unroll
    for (int ct = 0; ct < 4; ct++) {
        int ch = l15 + 16 * ct;
        bpj[ct] = b_proj[ch]; g2[ct] = ln2_g[ch]; b2[ct] = ln2_b[ch]; bfc2v[ct] = b_fc2[ch];
    }
    float bf1v[16];
    #pragma unroll
    for (int ct = 0; ct < 16; ct++) bf1v[ct] = b_fc1[ct * 16 + l15];

    __syncthreads();

    // ---- per-iteration global load (issues 3 fp8 uint2 loads + 16 x floats)
    auto LOADIT = [&](int itx, uint2* qv, uint2* gv, uint2* vv, float (*xvv)[4]) {
        const int tok0 = chunk * 1024 + (itx * 16 + w) * 16;
        const size_t rowb = (size_t)b * NT + tok0;
        const size_t goff = (rowb + l15) * 64;
        #pragma unroll
        for (int ks = 0; ks < 2; ks++) {
            qv[ks] = *(const uint2*)(qb8   + goff + ks * 32 + g * 8);
            gv[ks] = *(const uint2*)(gbuf8 + goff + ks * 32 + g * 8);
            vv[ks] = *(const uint2*)(vdb8  + goff + ks * 32 + g * 8);
        }
        #pragma unroll
        for (int ct = 0; ct < 4; ct++)
            #pragma unroll
            for (int r = 0; r < 4; r++)
                xvv[ct][r] = x[(rowb + g * 4 + r) * 64 + l15 + 16 * ct];
    };

    uint2 qv[2], gv[2], vv[2];
    float xv[4][4];
    LOADIT(0, qv, gv, vv, xv);

    #pragma unroll
    for (int it = 0; it < 4; ++it) {
        // ---- prefetch next iteration's loads before current compute
        uint2 qv2[2], gv2[2], vv2[2];
        float xv2[4][4];
        if (it < 3) LOADIT(it + 1, qv2, gv2, vv2, xv2);

        const int tok0 = chunk * 1024 + (it * 16 + w) * 16;
        const size_t rowb = (size_t)b * NT + tok0;

        // ---- decode fp8 activations
        float qf[2][8], vdf[2][8], ggf[2][8];
        #pragma unroll
        for (int ks = 0; ks < 2; ks++) {
            #pragma unroll
            for (int k = 0; k < 4; k++) {
                qf[ks][k]      = d8((unsigned char)(qv[ks].x >> (8 * k)));
                qf[ks][4 + k]  = d8((unsigned char)(qv[ks].y >> (8 * k)));
                ggf[ks][k]     = d8((unsigned char)(gv[ks].x >> (8 * k)));
                ggf[ks][4 + k] = d8((unsigned char)(gv[ks].y >> (8 * k)));
                vdf[ks][k]     = d8((unsigned char)(vv[ks].x >> (8 * k)));
                vdf[ks][4 + k] = d8((unsigned char)(vv[ks].y >> (8 * k)));
            }
        }

        // ---- phase A: q features + denominator via 2 MFMAs
        short8 Fqp[2], Fqn[2];
        f32x4 dn[2];
        #pragma unroll
        for (int h = 0; h < 2; h++) {
            #pragma unroll
            for (int j = 0; j < 8; j++) {
                float q = qf[h][j];
                Fqp[h][j] = bfs(safe_pow(q, pw3[h][j]));
                Fqn[h][j] = bfs(safe_pow(-q, pw3[h][j]));
            }
            f32x4 z4 = {0.f, 0.f, 0.f, 0.f};
            z4 = MFMA(Fqp[h], Kden[h][0], z4);
            dn[h] = MFMA(Fqn[h], Kden[h][1], z4);
        }

        // ---- phase B: attention MFMA (kv frags from LDS)
        f32x4 at[4];
        #pragma unroll
        for (int hs = 0; hs < 4; hs++) { f32x4 z4 = {0.f,0.f,0.f,0.f}; at[hs] = z4; }
        #pragma unroll
        for (int h = 0; h < 2; h++) {
            short8 b00 = *(const short8*)&wkv_s[(0 * 2 + h) * 2 + 0][l * 8];
            short8 b01 = *(const short8*)&wkv_s[(0 * 2 + h) * 2 + 1][l * 8];
            short8 b10 = *(const short8*)&wkv_s[(1 * 2 + h) * 2 + 0][l * 8];
            short8 b11 = *(const short8*)&wkv_s[(1 * 2 + h) * 2 + 1][l * 8];
            at[h*2+0] = MFMA(Fqp[h], b00, at[h*2+0]);
            at[h*2+0] = MFMA(Fqn[h], b01, at[h*2+0]);
            at[h*2+1] = MFMA(Fqn[h], b10, at[h*2+1]);
            at[h*2+1] = MFMA(Fqp[h], b11, at[h*2+1]);
        }

        // ---- phase C: z-scale via shfl of dn, transpose, + dwc, * gate
        #pragma unroll
        for (int hs = 0; hs < 4; hs++) {
            int h = hs >> 1, s = hs & 1;
            int cb = h * 32 + s * 16;
            #pragma unroll
            for (int r = 0; r < 4; r++) {
                float dv = __shfl(dn[h][r], g * 16 + s, 64);
                float zz = __builtin_amdgcn_rcpf(dv + 1e-6f);
                int tok = g * 4 + r;
                *(short*)(tb + tok * 128 + (((cb + l15) * 2) ^ ((tok & 7) << 4))) = bfs(at[hs][r] * zz);
            }
        }
        short8 Ap[2];
        #pragma unroll
        for (int ks = 0; ks < 2; ks++) {
            short8 t8 = *(short8*)(tb + l15 * 128 + ((ks * 64 + g * 16) ^ ((l15 & 7) << 4)));
            #pragma unroll
            for (int j = 0; j < 8; j++)
                Ap[ks][j] = bfs((sbf(t8[j]) + vdf[ks][j]) * ggf[ks][j]);
        }

        // ---- phase D: proj (frags from LDS)
        f32x4 pc[4];
        #pragma unroll
        for (int ct = 0; ct < 4; ct++) {
            short8 w0 = *(const short8*)&wp_s[ct * 2 + 0][l * 8];
            short8 w1 = *(const short8*)&wp_s[ct * 2 + 1][l * 8];
            f32x4 z4 = {0.f,0.f,0.f,0.f};
            z4 = MFMA(Ap[0], w0, z4);
            pc[ct] = MFMA(Ap[1], w1, z4);
        }

        // ---- phase E: residual + LN2 + write h2 transpose directly
        float xm[4][4];
        #pragma unroll
        for (int ct = 0; ct < 4; ct++)
            #pragma unroll
            for (int r = 0; r < 4; r++)
                xm[ct][r] = xv[ct][r] + pc[ct][r] + bpj[ct];
        #pragma unroll
        for (int r = 0; r < 4; r++) {
            float s1 = xm[0][r] + xm[1][r] + xm[2][r] + xm[3][r];
            float s2 = xm[0][r]*xm[0][r] + xm[1][r]*xm[1][r] + xm[2][r]*xm[2][r] + xm[3][r]*xm[3][r];
            #pragma unroll
            for (int m = 1; m < 16; m <<= 1) { s1 += __shfl_xor(s1, m, 64); s2 += __shfl_xor(s2, m, 64); }
            float mu = s1 * 0.015625f;
            float var = s2 * 0.015625f - mu * mu;
            float rs = rsqrtf(var + 1e-5f);
            int tok = g * 4 + r;
            #pragma unroll
            for (int ct = 0; ct < 4; ct++) {
                float h2 = (xm[ct][r] - mu) * rs * g2[ct] + b2[ct];
                *(short*)(tb + tok * 128 + (((ct * 16 + l15) * 2) ^ ((tok & 7) << 4))) = bfs(h2);
            }
        }
        short8 Ah[2];
        #pragma unroll
        for (int ks = 0; ks < 2; ks++)
            Ah[ks] = *(short8*)(tb + l15 * 128 + ((ks * 64 + g * 16) ^ ((l15 & 7) << 4)));

        // ---- phase G: fc1 + gelu + fc2 (all frags from LDS)
        f32x4 a2[4];
        #pragma unroll
        for (int ct = 0; ct < 4; ct++) { f32x4 z4 = {0.f,0.f,0.f,0.f}; a2[ct] = z4; }
        #pragma unroll
        for (int g4 = 0; g4 < 4; g4++) {
            f32x4 fc[4];
            #pragma unroll
            for (int ctl = 0; ctl < 4; ctl++) {
                int ct = g4 * 4 + ctl;
                short8 f0 = *(const short8*)(wf1_s + (ct * 2 + 0) * 512 + l * 8);
                short8 f1 = *(const short8*)(wf1_s + (ct * 2 + 1) * 512 + l * 8);
                f32x4 z4 = {0.f,0.f,0.f,0.f};
                z4 = MFMA(Ah[0], f0, z4);
                fc[ctl] = MFMA(Ah[1], f1, z4);
            }
            #pragma unroll
            for (int ctl = 0; ctl < 4; ctl++)
                #pragma unroll
                for (int r = 0; r < 4; r++) {
                    float mv = fc[ctl][r] + bf1v[g4 * 4 + ctl];
                    float gl = mv * __builtin_amdgcn_rcpf(1.f +
                        __builtin_amdgcn_exp2f(mv * (-2.30220825f - 0.10294385f * mv * mv)));
                    int tok = g * 4 + r;
                    *(short*)(tb + tok * 128 + (((ctl * 16 + l15) * 2) ^ ((tok & 7) << 4))) = bfs(gl);
                }
            #pragma unroll
            for (int ksl = 0; ksl < 2; ksl++) {
                short8 Ag = *(short8*)(tb + l15 * 128 + ((ksl * 64 + g * 16) ^ ((l15 & 7) << 4)));
                int ks = g4 * 2 + ksl;
                #pragma unroll
                for (int ct2 = 0; ct2 < 4; ct2++) {
                    short8 wv = *(const short8*)(wf2_s + (ct2 * 8 + ks) * 512 + l * 8);
                    a2[ct2] = MFMA(Ag, wv, a2[ct2]);
                }
            }
        }

        // ---- phase H: bounce through tbuf, plain f32x4 stores
        float* tb32 = (float*)tb;   // 2048 B = 16 tok x 32 ch f32
        #pragma unroll
        for (int half = 0; half < 2; ++half) {
            #pragma unroll
            for (int ctl = 0; ctl < 2; ++ctl) {
                int ct = half * 2 + ctl;
                #pragma unroll
                for (int r = 0; r < 4; r++)
                    tb32[(g * 4 + r) * 32 + ctl * 16 + l15] = xm[ct][r] + a2[ct][r] + bfc2v[ct];
            }
            #pragma unroll
            for (int i = 0; i < 2; ++i) {
                f32x4 v = *(f32x4*)&tb32[i * 256 + l * 4];
                *(f32x4*)(out + (rowb + i * 8 + (l >> 3)) * 64 + half * 32 + (l & 7) * 4) = v;
            }
        }

        // ---- rotate prefetched buffers
        #pragma unroll
        for (int ks = 0; ks < 2; ks++) { qv[ks] = qv2[ks]; gv[ks] = gv2[ks]; vv[ks] = vv2[ks]; }
        #pragma unroll
        for (int ct = 0; ct < 4; ct++)
            #pragma unroll
            for (int r = 0; r < 4; r++)
                xv[ct][r] = xv2[ct][r];
    }
}

// ---------------------------------------------------------------------------
extern "C" void kernel_launch(void* const* d_in, const int* in_sizes, int n_in,
                              void* d_out, int out_size, void* d_ws, size_t ws_size,
                              hipStream_t stream)
{
    const float* x       = (const float*)d_in[0];
    const float* ln1_g   = (const float*)d_in[3];
    const float* ln1_b   = (const float*)d_in[4];
    const float* w_qg    = (const float*)d_in[5];
    const float* w_kv    = (const float*)d_in[6];
    const float* pos     = (const float*)d_in[7];
    const float* scale_p = (const float*)d_in[8];
    const float* power_p = (const float*)d_in[9];
    const float* dwc_w   = (const float*)d_in[10];
    const float* dwc_b   = (const float*)d_in[11];
    const float* w_proj  = (const float*)d_in[12];
    const float* b_proj  = (const float*)d_in[13];
    const float* ln2_g   = (const float*)d_in[14];
    const float* ln2_b   = (const float*)d_in[15];
    const float* w_fc1   = (const float*)d_in[16];
    const float* b_fc1   = (const float*)d_in[17];
    const float* w_fc2   = (const float*)d_in[18];
    const float* b_fc2   = (const float*)d_in[19];
    float* out = (float*)d_out;

    // workspace layout: all activation intermediates fp8 -> footprint ~134MB
    size_t ntc = (size_t)NTOK * 64;
    unsigned char* qb8   = (unsigned char*)d_ws;
    unsigned char* vbuf8 = qb8 + ntc;
    unsigned char* gbuf8 = vbuf8 + ntc;
    unsigned char* vdb8  = gbuf8 + ntc;
    float* km_g = (float*)(vdb8 + ntc);              // [B][128]
    float* kv_g = km_g + (size_t)NB * 128;           // [B][4096]
    short* wqk_f = (short*)(kv_g + (size_t)NB * 4096);
    short* wf1_f = wqk_f + 16384;
    short* wf2_f = wf1_f + 16384;

    hipMemsetAsync(km_g, 0, ((size_t)NB * 128 + (size_t)NB * 4096) * sizeof(float), stream);

    k0_prep<<<dim3(192), 256, 0, stream>>>(w_qg, w_kv, w_fc1, w_fc2, wqk_f, wf1_f, wf2_f);
    k1_proj<<<dim3(32, NB), 256, 0, stream>>>(x, ln1_g, ln1_b, wqk_f, pos, scale_p, power_p,
                                              qb8, gbuf8, vbuf8, km_g, kv_g);
    k2_dwc<<<dim3(64, NB), 256, 0, stream>>>(vbuf8, dwc_w, dwc_b, vdb8);
    k3_main<<<dim3(16, NB), 1024, 0, stream>>>(x, qb8, gbuf8, vdb8, km_g, kv_g, power_p,
                                               w_proj, b_proj, ln2_g, ln2_b,
                                               wf1_f, wf2_f, b_fc1, b_fc2, out);
}